// Round 5
// baseline (73.053 us; speedup 1.0000x reference)
//
#include <hip/hip_runtime.h>

#define B_ 32
#define T_ 8192
#define D_ 128
#define MBLK 128
#define NCHUNK 64    // T_/MBLK

typedef __attribute__((ext_vector_type(8))) _Float16 half8;
typedef __attribute__((ext_vector_type(4))) float floatx4;

__device__ __forceinline__ float tanh_fast(float x) {
    float e = __expf(2.0f * x);
    return 1.0f - __fdividef(2.0f, e + 1.0f);
}

// K0 (fused prep): blocks 0-7 pack W1 MFMA B-fragments; blocks 8-23 compute bias.
// B[k][n]: lane l holds n = ni*16 + (l&15), k = kk*32 + (l>>4)*8 + j  (j=0..7).
__global__ void prep_kernel(const float* __restrict__ W1, half8* __restrict__ W1frag,
                            const float* __restrict__ dec, const float* __restrict__ W2,
                            float* __restrict__ bias) {
    int bid = blockIdx.x, tid = threadIdx.x;
    if (bid < 8) {
        int tg = bid * 256 + tid;   // (kk*8+ni)*64+lane
        int kk = tg >> 9, ni = (tg >> 6) & 7, lane = tg & 63;
        half8 h;
        #pragma unroll
        for (int j = 0; j < 8; ++j) {
            int k = kk * 32 + ((lane >> 4) * 8) + j;
            int n = ni * 16 + (lane & 15);
            h[j] = (_Float16)W1[k * 128 + n];
        }
        W1frag[tg] = h;
    } else {
        int b = (bid - 8) * 2 + (tid >> 7);
        int d = tid & 127;
        float acc = 0.f;
        for (int h = 0; h < 128; ++h)
            acc += dec[b * 128 + h] * W2[h * 128 + d];
        bias[b * 128 + d] = acc;
    }
}

// K2: f16 MFMA GEMM + tanh + V-dot + chunk softmax stats + chunk context partial.
// 512 threads = 8 waves; wave w owns rows [w*16, w*16+16); context from registers.
__global__ __launch_bounds__(512)
void main_kernel(const float* __restrict__ enc, const half8* __restrict__ W1frag,
                 const float* __restrict__ bias, const float* __restrict__ V,
                 float* __restrict__ out_w, float* __restrict__ m_part,
                 float* __restrict__ s_part, float* __restrict__ c_part)
{
    __shared__ __align__(16) half8 bfr[2048];       // 32 KB W1 fragments
    __shared__ __align__(16) float red[MBLK];       // raw logits
    __shared__ __align__(16) float c_red[8][128];   // 4 KB per-wave context partials

    const int tid = threadIdx.x;
    const int l = tid & 63;
    const int w = tid >> 6;
    const int g = l >> 4;            // k-group / col-group
    const int bid = blockIdx.x;
    const int b = bid >> 6;          // NCHUNK=64 chunks per batch
    const int chunk = bid & 63;
    const float* encp = enc + ((long)(b * T_) + chunk * MBLK) * D_;

    // A-fragments straight from global: lane l -> row w*16+(l&15),
    // k = kk*32 + g*8 + j. 2x float4 per kk, convert in-reg. Issued first (HBM).
    const int arow = w * 16 + (l & 15);
    const float* rowp = encp + arow * 128 + g * 8;
    half8 afr[4];
    #pragma unroll
    for (int kk = 0; kk < 4; ++kk) {
        float4 f0 = *(const float4*)(rowp + kk * 32);
        float4 f1 = *(const float4*)(rowp + kk * 32 + 4);
        half8 a;
        a[0] = (_Float16)f0.x; a[1] = (_Float16)f0.y;
        a[2] = (_Float16)f0.z; a[3] = (_Float16)f0.w;
        a[4] = (_Float16)f1.x; a[5] = (_Float16)f1.y;
        a[6] = (_Float16)f1.z; a[7] = (_Float16)f1.w;
        afr[kk] = a;
    }

    // stage W1 fragments cooperatively (32 KB, L2-hot)
    #pragma unroll
    for (int q = 0; q < 4; ++q)
        bfr[q * 512 + tid] = W1frag[q * 512 + tid];

    // bias / V (L2-hot), overlap with staging
    float bs[8], vv[8];
    #pragma unroll
    for (int ni = 0; ni < 8; ++ni) {
        int n = ni * 16 + (l & 15);
        bs[ni] = bias[b * 128 + n];
        vv[ni] = V[n];
    }
    __syncthreads();   // bfr ready

    floatx4 acc[8];
    #pragma unroll
    for (int ni = 0; ni < 8; ++ni) acc[ni] = (floatx4)0.0f;

    #pragma unroll
    for (int kk = 0; kk < 4; ++kk)
        #pragma unroll
        for (int ni = 0; ni < 8; ++ni)
            acc[ni] = __builtin_amdgcn_mfma_f32_16x16x32_f16(
                          afr[kk], bfr[(kk * 8 + ni) * 64 + l], acc[ni], 0, 0, 0);

    // epilogue: logit = sum_n tanh(score + bias[n]) * V[n]
    // C layout: col = ni*16 + (l&15), row = g*4 + j2   [m89-verified]
    float p[4];
    #pragma unroll
    for (int j2 = 0; j2 < 4; ++j2) {
        float q = 0.f;
        #pragma unroll
        for (int ni = 0; ni < 8; ++ni)
            q += tanh_fast(acc[ni][j2] + bs[ni]) * vv[ni];
        #pragma unroll
        for (int mk = 1; mk < 16; mk <<= 1)
            q += __shfl_xor(q, mk);
        p[j2] = q;   // all 16 lanes of group g hold row w*16+g*4+j2
    }
    if ((l & 15) == 0) {
        floatx4 v4 = {p[0], p[1], p[2], p[3]};
        *(floatx4*)(&red[w * 16 + g * 4]) = v4;
        *(floatx4*)(out_w + (long)b * T_ + chunk * MBLK + w * 16 + g * 4) = v4;
    }
    __syncthreads();   // red[] ready

    // chunk softmax stats — redundantly per wave (no extra barrier)
    float l0 = red[l], l1 = red[l + 64];
    float m = fmaxf(l0, l1);
    #pragma unroll
    for (int mk = 1; mk < 64; mk <<= 1) m = fmaxf(m, __shfl_xor(m, mk));
    {
        float s = __expf(l0 - m) + __expf(l1 - m);
        #pragma unroll
        for (int mk = 1; mk < 64; mk <<= 1) s += __shfl_xor(s, mk);
        if (tid == 0) { m_part[bid] = m; s_part[bid] = s; }
    }

    // context partial from registers: wave w covers rows [w*16, w*16+16).
    // lane holds row arow, cols kk*32+g*8+j; reduce over the 16 row-lanes.
    {
        float wgt = __expf(red[arow] - m);
        #pragma unroll
        for (int kk = 0; kk < 4; ++kk) {
            float cc[8];
            #pragma unroll
            for (int j = 0; j < 8; ++j) {
                cc[j] = wgt * (float)afr[kk][j];
                #pragma unroll
                for (int mk = 1; mk < 16; mk <<= 1)
                    cc[j] += __shfl_xor(cc[j], mk);
            }
            if ((l & 15) == 0) {
                floatx4 v0 = {cc[0], cc[1], cc[2], cc[3]};
                floatx4 v1 = {cc[4], cc[5], cc[6], cc[7]};
                *(floatx4*)(&c_red[w][kk * 32 + g * 8]) = v0;
                *(floatx4*)(&c_red[w][kk * 32 + g * 8 + 4]) = v1;
            }
        }
    }
    __syncthreads();
    if (tid < 128) {
        float s = 0.f;
        #pragma unroll
        for (int ww = 0; ww < 8; ++ww) s += c_red[ww][tid];
        c_part[(long)bid * 128 + tid] = s;
    }
}

// K3 (fused reduce+finalize): per batch — global (m,s), context, softmax weights.
__global__ __launch_bounds__(256)
void reduce_kernel(const float* __restrict__ m_part, const float* __restrict__ s_part,
                   const float* __restrict__ c_part, float* __restrict__ ctx,
                   float* __restrict__ out_w)
{
    __shared__ float sc[64];     // exp(m_w - m_g) per chunk
    __shared__ float stats[2];   // m_g, s_g
    int b = blockIdx.x, tid = threadIdx.x;

    if (tid < 64) {
        float m = m_part[b * 64 + tid];
        float mg = m;
        #pragma unroll
        for (int mk = 1; mk < 64; mk <<= 1) mg = fmaxf(mg, __shfl_xor(mg, mk));
        float e = __expf(m - mg);
        float s = s_part[b * 64 + tid] * e;
        #pragma unroll
        for (int mk = 1; mk < 64; mk <<= 1) s += __shfl_xor(s, mk);
        sc[tid] = e;
        if (tid == 0) { stats[0] = mg; stats[1] = s; }
    }
    __syncthreads();
    float m_g = stats[0], s_g = stats[1];
    float inv = __fdividef(1.0f, s_g);

    if (tid < 128) {
        float acc = 0.f;
        for (int ch = 0; ch < 64; ++ch)
            acc += c_part[((long)b * 64 + ch) * 128 + tid] * sc[ch];
        ctx[b * 128 + tid] = acc * inv;
    }

    float* ow = out_w + (long)b * T_;
    for (int i = tid; i < T_; i += 256)
        ow[i] = __expf(ow[i] - m_g) * inv;
}

extern "C" void kernel_launch(void* const* d_in, const int* in_sizes, int n_in,
                              void* d_out, int out_size, void* d_ws, size_t ws_size,
                              hipStream_t stream)
{
    const float* enc = (const float*)d_in[0];
    const float* dec = (const float*)d_in[1];
    const float* W1  = (const float*)d_in[2];
    const float* W2  = (const float*)d_in[3];
    const float* V   = (const float*)d_in[4];

    float* ctx  = (float*)d_out;          // [B, 128]
    float* outw = ctx + B_ * D_;          // [B, T]

    float* ws     = (float*)d_ws;
    float* bias   = ws;                   // 4096
    float* m_part = bias + 4096;          // 2048
    float* s_part = m_part + 2048;        // 2048
    float* c_part = s_part + 2048;        // 2048*128 = 262144
    half8* W1frag = (half8*)(c_part + (long)B_ * NCHUNK * 128);  // 32 KB, 16B-aligned

    prep_kernel<<<24, 256, 0, stream>>>(W1, W1frag, dec, W2, bias);
    main_kernel<<<B_ * NCHUNK, 512, 0, stream>>>(enc, W1frag, bias, V, outw, m_part, s_part, c_part);
    reduce_kernel<<<B_, 256, 0, stream>>>(m_part, s_part, c_part, ctx, outw);
}